// Round 6
// baseline (3850.525 us; speedup 1.0000x reference)
//
#include <hip/hip_runtime.h>

// ---------------------------------------------------------------------------
// GCN, 6 layers, N=1M nodes, E=16M edges.
// R11: R5-R10 fixed every latency/occupancy/L2-pollution knob; time stayed
// ~265us/layer. R10's decisive datum: FETCH 260->96MB (L2-locking verified)
// with ZERO time gain -> the wall is the random-request SERVICE rate:
// 16M gathers / 8 XCD / 636K cy ~= 3 random lines/cy/XCD, ~10x below the
// coalesced L2 stream rate. Fix is structural: remove the random-access
// class. Edges sorted by (dst_bucket 4K x src_subwindow 8K) = 245x123 bins;
// layer pass = per channel: stage subwindow to LDS (coalesced, reg-pipelined),
// edges do acc[dst&4095] += stage[src&8191] -- PURE LDS (divergence-immune);
// merge acc to global plane (coalesced atomics); epilogue kernel does
// norm/GEMV/ReLU on planes and re-zeros G. 3 passes for 3-ch layers, 1 for
// 1-ch (L1, L6-after-W6-fold). Build: 32K-bin hist/cursors via GLOBAL
// atomics (128KB > static-LDS cap), same transpose+scan machinery.
// Workspace ~100MB (hist aliases packed). Predict: k_pass 25-45us each,
// total 1617 -> ~800-1050us.
// ---------------------------------------------------------------------------

#define BT 256            // transpose/scan block size
#define NBLK 64           // partition blocks for hist/scatter
#define NBINS 32768       // (dst_bucket<<7)|src_subwindow, padded (245*123 real)
#define M (NBLK * NBINS)  // 2,097,152
#define BSHIFT 12         // 4096 dst nodes per bucket
#define BSIZE 4096
#define LMASK 4095
#define WSHIFT 13         // 8192 src nodes per subwindow
#define SMASK 8191

typedef float __attribute__((ext_vector_type(4))) f32x4;

__device__ __forceinline__ int edge_key(int s, int d) {
  return ((d >> BSHIFT) << 7) | (s >> WSHIFT);
}

// s0 = feat * norm
__global__ void k_init(const float* __restrict__ feat, const float* __restrict__ norm,
                       float* __restrict__ s0, int N) {
  int i = blockIdx.x * BT + threadIdx.x;
  if (i < N) s0[i] = feat[i] * norm[i];
}

// generic zero (grid-stride)
__global__ void k_zeroi(int* __restrict__ p, int n) {
  for (int i = blockIdx.x * blockDim.x + threadIdx.x; i < n; i += gridDim.x * blockDim.x)
    p[i] = 0;
}

// P1: histogram of (dst_bucket, src_subwindow) bins, global atomics
// (32K bins = 128KB exceeds the static-LDS cap; per-block row is L2-resident)
__global__ void k_ghist(const int* __restrict__ src, const int* __restrict__ dst,
                        int* __restrict__ histB, int E, int chunk) {
  int b = blockIdx.x;
  int* row = histB + (size_t)b * NBINS;
  int beg = b * chunk, end = min(beg + chunk, E);
  int i = beg + (int)threadIdx.x * 4;  // beg 16B-aligned (chunk % 4 == 0)
  for (; i + 3 < end; i += 1024 * 4) {
    int4 u = *(const int4*)(src + i);
    int4 v = *(const int4*)(dst + i);
    atomicAdd(&row[edge_key(u.x, v.x)], 1);
    atomicAdd(&row[edge_key(u.y, v.y)], 1);
    atomicAdd(&row[edge_key(u.z, v.z)], 1);
    atomicAdd(&row[edge_key(u.w, v.w)], 1);
  }
  for (; i < end; ++i) atomicAdd(&row[edge_key(src[i], dst[i])], 1);
}

// Tiled transpose: in[R][C] -> out[C][R]. R,C multiples of 64. grid(C/64,R/64)
__global__ void k_transp(const int* __restrict__ in, int* __restrict__ out, int R, int C) {
  __shared__ int tile[64][65];
  int c0 = blockIdx.x * 64, r0 = blockIdx.y * 64;
  int tx = threadIdx.x & 63, ty = threadIdx.x >> 6;  // 64 x 4
  for (int j = 0; j < 16; ++j) {
    int r = ty + j * 4;
    tile[r][tx] = in[(size_t)(r0 + r) * C + c0 + tx];
  }
  __syncthreads();
  for (int j = 0; j < 16; ++j) {
    int r = ty + j * 4;
    out[(size_t)(c0 + r) * R + r0 + tx] = tile[tx][r];
  }
}

// scan A: per-block sums
__global__ void k_blockSum(const int* __restrict__ data, int* __restrict__ partial, int Mlen) {
  __shared__ int tmp[BT];
  int i = blockIdx.x * BT + threadIdx.x;
  tmp[threadIdx.x] = (i < Mlen) ? data[i] : 0;
  __syncthreads();
  for (int off = BT / 2; off > 0; off >>= 1) {
    if (threadIdx.x < off) tmp[threadIdx.x] += tmp[threadIdx.x + off];
    __syncthreads();
  }
  if (threadIdx.x == 0) partial[blockIdx.x] = tmp[0];
}

// scan B: exclusive scan of partials in place (single block)
__global__ void k_scanPartials(int* __restrict__ partial, int nb) {
  __shared__ int tmp[BT];
  __shared__ int carry;
  int t = threadIdx.x;
  if (t == 0) carry = 0;
  __syncthreads();
  for (int base = 0; base < nb; base += BT) {
    int i = base + t;
    int v = (i < nb) ? partial[i] : 0;
    tmp[t] = v;
    __syncthreads();
    for (int off = 1; off < BT; off <<= 1) {
      int x = 0;
      if (t >= off) x = tmp[t - off];
      __syncthreads();
      tmp[t] += x;
      __syncthreads();
    }
    if (i < nb) partial[i] = tmp[t] - v + carry;
    __syncthreads();
    if (t == BT - 1) carry += tmp[BT - 1];
    __syncthreads();
  }
}

// scan C: final exclusive scan in place
__global__ void k_scanFinal(int* __restrict__ data, const int* __restrict__ partial, int Mlen) {
  __shared__ int tmp[BT];
  int t = threadIdx.x;
  int i = blockIdx.x * BT + t;
  int v = (i < Mlen) ? data[i] : 0;
  tmp[t] = v;
  __syncthreads();
  for (int off = 1; off < BT; off <<= 1) {
    int x = 0;
    if (t >= off) x = tmp[t - off];
    __syncthreads();
    tmp[t] += x;
    __syncthreads();
  }
  if (i < Mlen) data[i] = tmp[t] - v + partial[blockIdx.x];
}

// copy global bin starts (row 0 of scanT) BEFORE pscatter mutates cursors
__global__ void k_copyBin(const int* __restrict__ scanT, int* __restrict__ binStart, int E) {
  int i = blockIdx.x * 1024 + threadIdx.x;
  if (i < NBINS) binStart[i] = scanT[i];
  if (i == NBINS) binStart[NBINS] = E;
}

// P2: scatter packed edges, global-atomic cursors (scanT rows)
__global__ void k_pscatter(const int* __restrict__ src, const int* __restrict__ dst,
                           int* __restrict__ scanT, unsigned int* __restrict__ packed,
                           int E, int chunk) {
  int b = blockIdx.x;
  int* cur = scanT + (size_t)b * NBINS;
  int beg = b * chunk, end = min(beg + chunk, E);
  int i = beg + (int)threadIdx.x * 4;
  for (; i + 3 < end; i += 1024 * 4) {
    int4 u = *(const int4*)(src + i);
    int4 v = *(const int4*)(dst + i);
    int p;
    p = atomicAdd(&cur[edge_key(u.x, v.x)], 1);
    packed[p] = ((unsigned)(u.x & SMASK) << BSHIFT) | (unsigned)(v.x & LMASK);
    p = atomicAdd(&cur[edge_key(u.y, v.y)], 1);
    packed[p] = ((unsigned)(u.y & SMASK) << BSHIFT) | (unsigned)(v.y & LMASK);
    p = atomicAdd(&cur[edge_key(u.z, v.z)], 1);
    packed[p] = ((unsigned)(u.z & SMASK) << BSHIFT) | (unsigned)(v.z & LMASK);
    p = atomicAdd(&cur[edge_key(u.w, v.w)], 1);
    packed[p] = ((unsigned)(u.w & SMASK) << BSHIFT) | (unsigned)(v.w & LMASK);
  }
  for (; i < end; ++i) {
    int p = atomicAdd(&cur[edge_key(src[i], dst[i])], 1);
    packed[p] = ((unsigned)(src[i] & SMASK) << BSHIFT) | (unsigned)(dst[i] & LMASK);
  }
}

// --- layer pass: one channel, block = (bucket k, half s of subwindows) ---
// Stage subwindow (8K floats, 32KB) to LDS coalesced, reg-pipelined; edges
// are pure LDS: acc[dst&4095] += stage[src&8191]. Merge acc -> G plane.
__global__ __launch_bounds__(1024, 8) void k_pass(
    const int* __restrict__ binStart, const unsigned int* __restrict__ packed,
    const float* __restrict__ X, float* __restrict__ G, int N) {
  __shared__ float stage[8192];
  __shared__ float acc[4096];
  int t = threadIdx.x;
  for (int j = t; j < 4096; j += 1024) acc[j] = 0.0f;
  int NW = (N + SMASK) >> WSHIFT;          // 123 subwindows
  int k = blockIdx.x >> 1, s = blockIdx.x & 1;
  int WPB = (NW + 1) >> 1;                 // 62
  int wbeg = s * WPB, wend = min(NW, wbeg + WPB);
  int bbase = k << 7;
  // prime stage for wbeg
  float r[8];
  {
    int nb = wbeg << WSHIFT;
#pragma unroll
    for (int j = 0; j < 8; ++j) {
      int idx = nb + t + (j << 10);
      r[j] = (idx < N) ? X[idx] : 0.0f;
    }
  }
#pragma unroll
  for (int j = 0; j < 8; ++j) stage[t + (j << 10)] = r[j];
  __syncthreads();
  for (int w = wbeg; w < wend; ++w) {
    bool more = (w + 1 < wend);
    float r2[8];
    if (more) {                            // issue next stage early (T14)
      int nb = (w + 1) << WSHIFT;
#pragma unroll
      for (int j = 0; j < 8; ++j) {
        int idx = nb + t + (j << 10);
        r2[j] = (idx < N) ? X[idx] : 0.0f;
      }
    }
    int beg = binStart[bbase + w], end = binStart[bbase + w + 1];
    for (int i = beg + t; i < end; i += 1024) {
      unsigned p = __builtin_nontemporal_load(packed + i);
      atomicAdd(&acc[p & LMASK], stage[p >> BSHIFT]);
    }
    __syncthreads();                       // edge reads of stage done
    if (more) {
#pragma unroll
      for (int j = 0; j < 8; ++j) stage[t + (j << 10)] = r2[j];
    }
    __syncthreads();                       // new stage visible
  }
  int gb = k << BSHIFT;
  for (int j = t; j < 4096; j += 1024) atomicAdd(&G[gb + j], acc[j]);
}

// --- epilogues: norm/GEMV/ReLU on planes; re-zero G for the next layer ---

// L1 (1->3): pre = G0*n; X_c = relu(pre*W1[c]+b1[c]) * n
__global__ void k_epi1(float* __restrict__ G0, const float* __restrict__ norm,
                       const float* __restrict__ W1, const float* __restrict__ b1,
                       float* __restrict__ X0, float* __restrict__ X1, float* __restrict__ X2,
                       int N) {
  int i = blockIdx.x * 1024 + threadIdx.x;
  if (i >= N) return;
  float n = norm[i];
  float pre = G0[i] * n;
  G0[i] = 0.0f;
  X0[i] = fmaxf(0.0f, pre * W1[0] + b1[0]) * n;
  X1[i] = fmaxf(0.0f, pre * W1[1] + b1[1]) * n;
  X2[i] = fmaxf(0.0f, pre * W1[2] + b1[2]) * n;
}

// L2-4 (3->3)
__global__ void k_epi3(float* __restrict__ G0, float* __restrict__ G1, float* __restrict__ G2,
                       const float* __restrict__ norm, const float* __restrict__ W,
                       const float* __restrict__ bias,
                       float* __restrict__ X0, float* __restrict__ X1, float* __restrict__ X2,
                       int N) {
  int i = blockIdx.x * 1024 + threadIdx.x;
  if (i >= N) return;
  float n = norm[i];
  float x0 = G0[i] * n, x1 = G1[i] * n, x2 = G2[i] * n;
  G0[i] = 0.0f; G1[i] = 0.0f; G2[i] = 0.0f;
  float h0 = fmaxf(0.0f, x0 * W[0] + x1 * W[3] + x2 * W[6] + bias[0]);
  float h1 = fmaxf(0.0f, x0 * W[1] + x1 * W[4] + x2 * W[7] + bias[1]);
  float h2 = fmaxf(0.0f, x0 * W[2] + x1 * W[5] + x2 * W[8] + bias[2]);
  X0[i] = h0 * n; X1[i] = h1 * n; X2[i] = h2 * n;
}

// L5 (3->3) + W6 fold: sB = (relu(agg*n @ W5 + b5) @ W6) * n
__global__ void k_epi5(float* __restrict__ G0, float* __restrict__ G1, float* __restrict__ G2,
                       const float* __restrict__ norm, const float* __restrict__ W5,
                       const float* __restrict__ b5, const float* __restrict__ W6,
                       float* __restrict__ sB, int N) {
  int i = blockIdx.x * 1024 + threadIdx.x;
  if (i >= N) return;
  float n = norm[i];
  float x0 = G0[i] * n, x1 = G1[i] * n, x2 = G2[i] * n;
  G0[i] = 0.0f; G1[i] = 0.0f; G2[i] = 0.0f;
  float h0 = fmaxf(0.0f, x0 * W5[0] + x1 * W5[3] + x2 * W5[6] + b5[0]);
  float h1 = fmaxf(0.0f, x0 * W5[1] + x1 * W5[4] + x2 * W5[7] + b5[1]);
  float h2 = fmaxf(0.0f, x0 * W5[2] + x1 * W5[5] + x2 * W5[8] + b5[2]);
  sB[i] = (h0 * W6[0] + h1 * W6[1] + h2 * W6[2]) * n;
}

// L6 (scalar): out = relu(G0*n + b6)
__global__ void k_epi6(const float* __restrict__ G0, const float* __restrict__ norm,
                       const float* __restrict__ b6, float* __restrict__ out, int N) {
  int i = blockIdx.x * 1024 + threadIdx.x;
  if (i >= N) return;
  out[i] = fmaxf(0.0f, G0[i] * norm[i] + b6[0]);
}

extern "C" void kernel_launch(void* const* d_in, const int* in_sizes, int n_in,
                              void* d_out, int out_size, void* d_ws, size_t ws_size,
                              hipStream_t stream) {
  const float* feat = (const float*)d_in[0];
  const float* norm = (const float*)d_in[1];
  const int* src = (const int*)d_in[2];
  const int* dst = (const int*)d_in[3];
  const float* W1 = (const float*)d_in[4];
  const float* b1 = (const float*)d_in[5];
  const float* W2 = (const float*)d_in[6];
  const float* b2 = (const float*)d_in[7];
  const float* W3 = (const float*)d_in[8];
  const float* b3 = (const float*)d_in[9];
  const float* W4 = (const float*)d_in[10];
  const float* b4 = (const float*)d_in[11];
  const float* W5 = (const float*)d_in[12];
  const float* b5 = (const float*)d_in[13];
  const float* W6 = (const float*)d_in[14];
  const float* b6 = (const float*)d_in[15];
  float* out = (float*)d_out;

  const int N = in_sizes[0];
  const int E = in_sizes[2];
  const int nbNode = (N + BT - 1) / BT;
  const int nBkt = (N + BSIZE - 1) >> BSHIFT;                 // 245
  const int chunk = (((E + NBLK - 1) / NBLK) + 3) & ~3;       // 16B-aligned chunks
  const int nbE = (N + 1023) / 1024;                          // epilogue grid

  // Workspace (~100.2 MB):
  //   packed[E] u32 (64MB; histB/histT 8+8MB alias inside, dead pre-scatter)
  // | scanT[M] (8MB) | partial[8192] | binStart[NBINS+1] | s0[N] | X[3N] | G[3N]
  unsigned int* packed = (unsigned int*)d_ws;
  int* histB = (int*)packed;            // build-phase only
  int* histT = histB + (size_t)M;       // build-phase only
  int* scanT = (int*)(packed + (size_t)E);
  int* partial = scanT + (size_t)M;
  int* binStart = partial + 8192;
  float* s0 = (float*)(binStart + NBINS + 1);
  float* X = s0 + (size_t)N;
  float* G = X + (size_t)3 * N;
  float* X0 = X, *X1 = X + N, *X2 = X + 2 * (size_t)N;
  float* G0 = G, *G1 = G + N, *G2 = G + 2 * (size_t)N;

  // --- Build (dst_bucket, src_subwindow)-sorted edge list ---
  k_init<<<nbNode, BT, 0, stream>>>(feat, norm, s0, N);
  k_zeroi<<<2048, 1024, 0, stream>>>(histB, M);
  k_zeroi<<<2048, 1024, 0, stream>>>((int*)G, 3 * N);
  k_ghist<<<NBLK, 1024, 0, stream>>>(src, dst, histB, E, chunk);
  {
    dim3 g1(NBINS / 64, NBLK / 64);  // histB[64][32768] -> histT[32768][64]
    k_transp<<<g1, BT, 0, stream>>>(histB, histT, NBLK, NBINS);
  }
  k_blockSum<<<M / BT, BT, 0, stream>>>(histT, partial, M);
  k_scanPartials<<<1, BT, 0, stream>>>(partial, M / BT);
  k_scanFinal<<<M / BT, BT, 0, stream>>>(histT, partial, M);
  {
    dim3 g2(NBLK / 64, NBINS / 64);  // histT[32768][64] (scanned) -> scanT[64][32768]
    k_transp<<<g2, BT, 0, stream>>>(histT, scanT, NBINS, NBLK);
  }
  k_copyBin<<<(NBINS + 1024) / 1024, 1024, 0, stream>>>(scanT, binStart, E);
  k_pscatter<<<NBLK, 1024, 0, stream>>>(src, dst, scanT, packed, E, chunk);

  const int gPass = nBkt * 2;  // (bucket, half-windows)

  // --- Layer 1 (1ch) ---
  k_pass<<<gPass, 1024, 0, stream>>>(binStart, packed, s0, G0, N);
  k_epi1<<<nbE, 1024, 0, stream>>>(G0, norm, W1, b1, X0, X1, X2, N);
  // --- Layers 2-4 (3ch) ---
  k_pass<<<gPass, 1024, 0, stream>>>(binStart, packed, X0, G0, N);
  k_pass<<<gPass, 1024, 0, stream>>>(binStart, packed, X1, G1, N);
  k_pass<<<gPass, 1024, 0, stream>>>(binStart, packed, X2, G2, N);
  k_epi3<<<nbE, 1024, 0, stream>>>(G0, G1, G2, norm, W2, b2, X0, X1, X2, N);
  k_pass<<<gPass, 1024, 0, stream>>>(binStart, packed, X0, G0, N);
  k_pass<<<gPass, 1024, 0, stream>>>(binStart, packed, X1, G1, N);
  k_pass<<<gPass, 1024, 0, stream>>>(binStart, packed, X2, G2, N);
  k_epi3<<<nbE, 1024, 0, stream>>>(G0, G1, G2, norm, W3, b3, X0, X1, X2, N);
  k_pass<<<gPass, 1024, 0, stream>>>(binStart, packed, X0, G0, N);
  k_pass<<<gPass, 1024, 0, stream>>>(binStart, packed, X1, G1, N);
  k_pass<<<gPass, 1024, 0, stream>>>(binStart, packed, X2, G2, N);
  k_epi3<<<nbE, 1024, 0, stream>>>(G0, G1, G2, norm, W4, b4, X0, X1, X2, N);
  // --- Layer 5 (3ch, W6 folded) -> sB in s0 buffer ---
  k_pass<<<gPass, 1024, 0, stream>>>(binStart, packed, X0, G0, N);
  k_pass<<<gPass, 1024, 0, stream>>>(binStart, packed, X1, G1, N);
  k_pass<<<gPass, 1024, 0, stream>>>(binStart, packed, X2, G2, N);
  k_epi5<<<nbE, 1024, 0, stream>>>(G0, G1, G2, norm, W5, b5, W6, s0, N);
  // --- Layer 6 (1ch) ---
  k_pass<<<gPass, 1024, 0, stream>>>(binStart, packed, s0, G0, N);
  k_epi6<<<nbE, 1024, 0, stream>>>(G0, norm, b6, out, N);
}

// Round 7
// 3229.651 us; speedup vs baseline: 1.1922x; 1.1922x over previous
//
#include <hip/hip_runtime.h>

// ---------------------------------------------------------------------------
// GCN, 6 layers, N=1M nodes, E=16M edges.
// R12: six-round synthesis. R10 proved divergent L2 requests are the wall
// (~3-4 req/cy/XCD, HIT OR MISS: FETCH 260->96MB, time flat). R11 proved
// (a) pure-LDS per-edge path works (~170us for ONE channel) and (b) global
// 32K-bin scatter = 15x write amplification (2M open lines >> L2, 885us).
// R12 = combined 3-channel LDS pass + fully L2-local two-level build:
//  - X as float4[N]; pass: bucket 8192 dst (acc 96KB) x 2048-node windows
//    (stage 32KB) = 128KB LDS; grid 123x2 halves; per edge 1 ds_read_b128 +
//    3 LDS atomicAdd; stage = coalesced streams (2GB/layer L2 ~ 58us).
//  - Build A (R9-verified shape): LDS-hist/cursor sort to 984 bins
//    (bucket123 x src-sb8); packed1 = src17<<13|dst13 (30b; sb from bin).
//    262K write streams = 17MB open lines, L2-fits.
//  - Build B: per-bucket refine to 2048-node windows: 512-bin LDS hist +
//    scan + scatter into the bucket's own ~520KB range (L2-resident).
//  - 3 bucket-chunks so packed1-chunk (26MB) aliases X/G; peak ws ~96MB.
// Predict: k_pass3 ~90-140us x4, k_pass1 ~40-60, build < 200us total,
// grand total ~850-1000us.
// packed2 = (src&2047)<<13 | (dst&8191); binStart2[(k<<9)+w], w=src>>11.
// ---------------------------------------------------------------------------

#define BT 256            // build-kernel block size
#define NBLK 256          // partition blocks (phase A)
#define NBINS_A 1024      // (dst>>13)<<3 | (src>>17); real 123*8=984
#define MA (NBLK * NBINS_A)  // 262144
#define NBKT 123          // dst buckets of 8192
#define BSHIFT 13
#define DMASK 8191
#define WSHIFT 11         // 2048-node src windows
#define SMASK 2047
#define NW 489            // ceil(1e6/2048)
#define NWH 245           // window split point
#define GP 1007616        // padded G plane length = NBKT*8192

typedef float __attribute__((ext_vector_type(4))) f32x4;

__device__ __forceinline__ int keyA(int s, int d) {
  return (int)((((unsigned)d >> BSHIFT) << 3) | ((unsigned)s >> 17));
}

// s0 = feat * norm
__global__ void k_init(const float* __restrict__ feat, const float* __restrict__ norm,
                       float* __restrict__ s0, int N) {
  int i = blockIdx.x * BT + threadIdx.x;
  if (i < N) s0[i] = feat[i] * norm[i];
}

// generic zero (grid-stride)
__global__ void k_zeroi(int* __restrict__ p, int n) {
  for (int i = blockIdx.x * blockDim.x + threadIdx.x; i < n; i += gridDim.x * blockDim.x)
    p[i] = 0;
}

// Phase A P1: per-block LDS histogram of (bucket, src_sb) bins
__global__ void k_phist(const int* __restrict__ src, const int* __restrict__ dst,
                        int* __restrict__ histB, int E, int chunk) {
  __shared__ int h[NBINS_A];
  for (int i = threadIdx.x; i < NBINS_A; i += BT) h[i] = 0;
  __syncthreads();
  int b = blockIdx.x;
  int beg = b * chunk, end = min(beg + chunk, E);
  int i = beg + (int)threadIdx.x * 4;  // beg 16B-aligned (chunk % 4 == 0)
  for (; i + 3 < end; i += BT * 4) {
    int4 u = *(const int4*)(src + i);
    int4 v = *(const int4*)(dst + i);
    atomicAdd(&h[keyA(u.x, v.x)], 1);
    atomicAdd(&h[keyA(u.y, v.y)], 1);
    atomicAdd(&h[keyA(u.z, v.z)], 1);
    atomicAdd(&h[keyA(u.w, v.w)], 1);
  }
  for (; i < end; ++i) atomicAdd(&h[keyA(src[i], dst[i])], 1);
  __syncthreads();
  for (int k = threadIdx.x; k < NBINS_A; k += BT) histB[b * NBINS_A + k] = h[k];
}

// Tiled transpose: in[R][C] -> out[C][R]. R,C multiples of 64. grid(C/64,R/64)
__global__ void k_transp(const int* __restrict__ in, int* __restrict__ out, int R, int C) {
  __shared__ int tile[64][65];
  int c0 = blockIdx.x * 64, r0 = blockIdx.y * 64;
  int tx = threadIdx.x & 63, ty = threadIdx.x >> 6;  // 64 x 4
  for (int j = 0; j < 16; ++j) {
    int r = ty + j * 4;
    tile[r][tx] = in[(size_t)(r0 + r) * C + c0 + tx];
  }
  __syncthreads();
  for (int j = 0; j < 16; ++j) {
    int r = ty + j * 4;
    out[(size_t)(c0 + r) * R + r0 + tx] = tile[tx][r];
  }
}

// scan A: per-block sums
__global__ void k_blockSum(const int* __restrict__ data, int* __restrict__ partial, int Mlen) {
  __shared__ int tmp[BT];
  int i = blockIdx.x * BT + threadIdx.x;
  tmp[threadIdx.x] = (i < Mlen) ? data[i] : 0;
  __syncthreads();
  for (int off = BT / 2; off > 0; off >>= 1) {
    if (threadIdx.x < off) tmp[threadIdx.x] += tmp[threadIdx.x + off];
    __syncthreads();
  }
  if (threadIdx.x == 0) partial[blockIdx.x] = tmp[0];
}

// scan B: exclusive scan of partials in place (single block)
__global__ void k_scanPartials(int* __restrict__ partial, int nb) {
  __shared__ int tmp[BT];
  __shared__ int carry;
  int t = threadIdx.x;
  if (t == 0) carry = 0;
  __syncthreads();
  for (int base = 0; base < nb; base += BT) {
    int i = base + t;
    int v = (i < nb) ? partial[i] : 0;
    tmp[t] = v;
    __syncthreads();
    for (int off = 1; off < BT; off <<= 1) {
      int x = 0;
      if (t >= off) x = tmp[t - off];
      __syncthreads();
      tmp[t] += x;
      __syncthreads();
    }
    if (i < nb) partial[i] = tmp[t] - v + carry;
    __syncthreads();
    if (t == BT - 1) carry += tmp[BT - 1];
    __syncthreads();
  }
}

// scan C: final exclusive scan in place
__global__ void k_scanFinal(int* __restrict__ data, const int* __restrict__ partial, int Mlen) {
  __shared__ int tmp[BT];
  int t = threadIdx.x;
  int i = blockIdx.x * BT + t;
  int v = (i < Mlen) ? data[i] : 0;
  tmp[t] = v;
  __syncthreads();
  for (int off = 1; off < BT; off <<= 1) {
    int x = 0;
    if (t >= off) x = tmp[t - off];
    __syncthreads();
    tmp[t] += x;
    __syncthreads();
  }
  if (i < Mlen) data[i] = tmp[t] - v + partial[blockIdx.x];
}

// Phase A P2 (per bucket-chunk): scatter packed1 with LDS cursors.
// packed1 = (src&0x1FFFF)<<13 | (dst&8191)  (30 bits; src top 3b = bin sb)
__global__ void k_pscatterC(const int* __restrict__ src, const int* __restrict__ dst,
                            const int* __restrict__ scanT, unsigned int* __restrict__ packed1C,
                            int E, int chunk, int kLo, int kHi) {
  __shared__ int cur[NBINS_A];
  int b = blockIdx.x;
  for (int k = threadIdx.x; k < NBINS_A; k += BT) cur[k] = scanT[b * NBINS_A + k];
  __syncthreads();
  int chunkBase = scanT[kLo << 3];  // row 0 = global bin starts
  int beg = b * chunk, end = min(beg + chunk, E);
#define SCAT1(S, D)                                                         \
  {                                                                         \
    int kb = (int)((unsigned)(D) >> BSHIFT);                                \
    if (kb >= kLo && kb < kHi) {                                            \
      int key = (kb << 3) | (int)((unsigned)(S) >> 17);                     \
      int pos = atomicAdd(&cur[key], 1);                                    \
      packed1C[pos - chunkBase] =                                           \
          (((unsigned)(S) & 0x1FFFFu) << BSHIFT) | ((unsigned)(D) & DMASK); \
    }                                                                       \
  }
  int i = beg + (int)threadIdx.x * 4;
  for (; i + 3 < end; i += BT * 4) {
    int4 u = *(const int4*)(src + i);
    int4 v = *(const int4*)(dst + i);
    SCAT1(u.x, v.x) SCAT1(u.y, v.y) SCAT1(u.z, v.z) SCAT1(u.w, v.w)
  }
  for (; i < end; ++i) SCAT1(src[i], dst[i]);
#undef SCAT1
}

// Phase B: per-bucket refine to 2048-node windows. One block per bucket.
// w = sb*64 + (src17>>11); scatter into the bucket's own (L2-resident) range.
// packed2 = (src&2047)<<13 | (dst&8191)
__global__ __launch_bounds__(1024) void k_refine(
    const int* __restrict__ bA, const unsigned int* __restrict__ packed1C,
    unsigned int* __restrict__ packed2, int* __restrict__ binStart2,
    int kLo, int E) {
  __shared__ int hist[512], sc[512], cur[512];
  int t = threadIdx.x;
  int k = kLo + blockIdx.x;
  int chunkBase = bA[kLo << 3];
  if (t < 512) hist[t] = 0;
  __syncthreads();
  for (int sb = 0; sb < 8; ++sb) {
    int lo = bA[(k << 3) + sb], hi = bA[(k << 3) + sb + 1];
    for (int i = lo + t; i < hi; i += 1024) {
      unsigned p = packed1C[i - chunkBase];
      atomicAdd(&hist[(sb << 6) | (p >> 24)], 1);
    }
  }
  __syncthreads();
  if (t < 512) sc[t] = hist[t];
  __syncthreads();
  for (int off = 1; off < 512; off <<= 1) {
    int v = 0;
    if (t >= off && t < 512) v = sc[t - off];
    __syncthreads();
    if (t < 512) sc[t] += v;
    __syncthreads();
  }
  int bucketBase = bA[k << 3];
  if (t < 512) {
    int ex = bucketBase + sc[t] - hist[t];  // exclusive scan + global base
    cur[t] = ex;
    binStart2[(k << 9) + t] = ex;
  }
  if (k == NBKT - 1 && t == 0) binStart2[NBKT << 9] = E;
  __syncthreads();
  for (int sb = 0; sb < 8; ++sb) {
    int lo = bA[(k << 3) + sb], hi = bA[(k << 3) + sb + 1];
    for (int i = lo + t; i < hi; i += 1024) {
      unsigned p = packed1C[i - chunkBase];
      int w = (sb << 6) | (int)(p >> 24);
      int pos = atomicAdd(&cur[w], 1);
      packed2[pos] = (((p >> BSHIFT) & SMASK) << BSHIFT) | (p & DMASK);
    }
  }
}

// --- 3-channel pass: block = (bucket k, window-half s). LDS-only per-edge. ---
__global__ __launch_bounds__(1024) void k_pass3(
    const int* __restrict__ binStart2, const unsigned int* __restrict__ packed,
    const f32x4* __restrict__ X, float* __restrict__ G0, float* __restrict__ G1,
    float* __restrict__ G2, int N) {
  __shared__ f32x4 stage[2048];                   // 32 KB
  __shared__ float a0[8192], a1[8192], a2[8192];  // 96 KB
  int t = threadIdx.x;
  int k = blockIdx.x >> 1, s = blockIdx.x & 1;
  for (int j = t; j < 8192; j += 1024) { a0[j] = 0.0f; a1[j] = 0.0f; a2[j] = 0.0f; }
  int wbeg = s ? NWH : 0, wend = s ? NW : NWH;
  f32x4 z = {0.0f, 0.0f, 0.0f, 0.0f};
  f32x4 r0, r1;
  {
    int nb = wbeg << WSHIFT;
    int i0 = nb + t, i1 = nb + 1024 + t;
    r0 = (i0 < N) ? X[i0] : z;
    r1 = (i1 < N) ? X[i1] : z;
  }
  stage[t] = r0;
  stage[t + 1024] = r1;
  __syncthreads();
  for (int w = wbeg; w < wend; ++w) {
    bool more = (w + 1 < wend);
    f32x4 n0 = z, n1 = z;
    if (more) {  // issue next-window stage loads early (hide under edge loop)
      int nb = (w + 1) << WSHIFT;
      int i0 = nb + t, i1 = nb + 1024 + t;
      n0 = (i0 < N) ? X[i0] : z;
      n1 = (i1 < N) ? X[i1] : z;
    }
    int idx = (k << 9) + w;
    int beg = binStart2[idx], end = binStart2[idx + 1];
    for (int i = beg + t; i < end; i += 1024) {
      unsigned p = __builtin_nontemporal_load(packed + i);
      f32x4 m = stage[p >> BSHIFT];
      int loc = p & DMASK;
      atomicAdd(&a0[loc], m.x);
      atomicAdd(&a1[loc], m.y);
      atomicAdd(&a2[loc], m.z);
    }
    __syncthreads();
    if (more) { stage[t] = n0; stage[t + 1024] = n1; }
    __syncthreads();
  }
  int gb = k << BSHIFT;
  for (int j = t; j < 8192; j += 1024) {
    atomicAdd(&G0[gb + j], a0[j]);
    atomicAdd(&G1[gb + j], a1[j]);
    atomicAdd(&G2[gb + j], a2[j]);
  }
}

// --- scalar pass (layers 1 and 6 inputs) ---
__global__ __launch_bounds__(1024) void k_pass1(
    const int* __restrict__ binStart2, const unsigned int* __restrict__ packed,
    const float* __restrict__ sIn, float* __restrict__ G0, int N) {
  __shared__ float stage[2048];  // 8 KB
  __shared__ float a[8192];      // 32 KB
  int t = threadIdx.x;
  int k = blockIdx.x >> 1, s = blockIdx.x & 1;
  for (int j = t; j < 8192; j += 1024) a[j] = 0.0f;
  int wbeg = s ? NWH : 0, wend = s ? NW : NWH;
  float r0, r1;
  {
    int nb = wbeg << WSHIFT;
    int i0 = nb + t, i1 = nb + 1024 + t;
    r0 = (i0 < N) ? sIn[i0] : 0.0f;
    r1 = (i1 < N) ? sIn[i1] : 0.0f;
  }
  stage[t] = r0;
  stage[t + 1024] = r1;
  __syncthreads();
  for (int w = wbeg; w < wend; ++w) {
    bool more = (w + 1 < wend);
    float n0 = 0.0f, n1 = 0.0f;
    if (more) {
      int nb = (w + 1) << WSHIFT;
      int i0 = nb + t, i1 = nb + 1024 + t;
      n0 = (i0 < N) ? sIn[i0] : 0.0f;
      n1 = (i1 < N) ? sIn[i1] : 0.0f;
    }
    int idx = (k << 9) + w;
    int beg = binStart2[idx], end = binStart2[idx + 1];
    for (int i = beg + t; i < end; i += 1024) {
      unsigned p = __builtin_nontemporal_load(packed + i);
      atomicAdd(&a[p & DMASK], stage[p >> BSHIFT]);
    }
    __syncthreads();
    if (more) { stage[t] = n0; stage[t + 1024] = n1; }
    __syncthreads();
  }
  int gb = k << BSHIFT;
  for (int j = t; j < 8192; j += 1024) atomicAdd(&G0[gb + j], a[j]);
}

// --- epilogues: norm/GEMV/ReLU; re-zero G planes for the next layer ---

__global__ void k_epi1(float* __restrict__ G0, const float* __restrict__ norm,
                       const float* __restrict__ W1, const float* __restrict__ b1,
                       f32x4* __restrict__ X, int N) {
  int i = blockIdx.x * 1024 + threadIdx.x;
  if (i >= N) return;
  float n = norm[i];
  float pre = G0[i] * n;
  G0[i] = 0.0f;
  f32x4 o = {fmaxf(0.0f, pre * W1[0] + b1[0]) * n, fmaxf(0.0f, pre * W1[1] + b1[1]) * n,
             fmaxf(0.0f, pre * W1[2] + b1[2]) * n, 0.0f};
  X[i] = o;
}

__global__ void k_epi3(float* __restrict__ G0, float* __restrict__ G1, float* __restrict__ G2,
                       const float* __restrict__ norm, const float* __restrict__ W,
                       const float* __restrict__ bias, f32x4* __restrict__ X, int N) {
  int i = blockIdx.x * 1024 + threadIdx.x;
  if (i >= N) return;
  float n = norm[i];
  float x0 = G0[i] * n, x1 = G1[i] * n, x2 = G2[i] * n;
  G0[i] = 0.0f; G1[i] = 0.0f; G2[i] = 0.0f;
  float h0 = fmaxf(0.0f, x0 * W[0] + x1 * W[3] + x2 * W[6] + bias[0]);
  float h1 = fmaxf(0.0f, x0 * W[1] + x1 * W[4] + x2 * W[7] + bias[1]);
  float h2 = fmaxf(0.0f, x0 * W[2] + x1 * W[5] + x2 * W[8] + bias[2]);
  f32x4 o = {h0 * n, h1 * n, h2 * n, 0.0f};
  X[i] = o;
}

__global__ void k_epi5(float* __restrict__ G0, float* __restrict__ G1, float* __restrict__ G2,
                       const float* __restrict__ norm, const float* __restrict__ W5,
                       const float* __restrict__ b5, const float* __restrict__ W6,
                       float* __restrict__ sB, int N) {
  int i = blockIdx.x * 1024 + threadIdx.x;
  if (i >= N) return;
  float n = norm[i];
  float x0 = G0[i] * n, x1 = G1[i] * n, x2 = G2[i] * n;
  G0[i] = 0.0f; G1[i] = 0.0f; G2[i] = 0.0f;
  float h0 = fmaxf(0.0f, x0 * W5[0] + x1 * W5[3] + x2 * W5[6] + b5[0]);
  float h1 = fmaxf(0.0f, x0 * W5[1] + x1 * W5[4] + x2 * W5[7] + b5[1]);
  float h2 = fmaxf(0.0f, x0 * W5[2] + x1 * W5[5] + x2 * W5[8] + b5[2]);
  sB[i] = (h0 * W6[0] + h1 * W6[1] + h2 * W6[2]) * n;
}

__global__ void k_epi6(const float* __restrict__ G0, const float* __restrict__ norm,
                       const float* __restrict__ b6, float* __restrict__ out, int N) {
  int i = blockIdx.x * 1024 + threadIdx.x;
  if (i >= N) return;
  out[i] = fmaxf(0.0f, G0[i] * norm[i] + b6[0]);
}

extern "C" void kernel_launch(void* const* d_in, const int* in_sizes, int n_in,
                              void* d_out, int out_size, void* d_ws, size_t ws_size,
                              hipStream_t stream) {
  const float* feat = (const float*)d_in[0];
  const float* norm = (const float*)d_in[1];
  const int* src = (const int*)d_in[2];
  const int* dst = (const int*)d_in[3];
  const float* W1 = (const float*)d_in[4];
  const float* b1 = (const float*)d_in[5];
  const float* W2 = (const float*)d_in[6];
  const float* b2 = (const float*)d_in[7];
  const float* W3 = (const float*)d_in[8];
  const float* b3 = (const float*)d_in[9];
  const float* W4 = (const float*)d_in[10];
  const float* b4 = (const float*)d_in[11];
  const float* W5 = (const float*)d_in[12];
  const float* b5 = (const float*)d_in[13];
  const float* W6 = (const float*)d_in[14];
  const float* b6 = (const float*)d_in[15];
  float* out = (float*)d_out;

  const int N = in_sizes[0];
  const int E = in_sizes[2];
  const int chunk = (((E + NBLK - 1) / NBLK) + 3) & ~3;  // 16B-aligned
  const int nbE = (N + 1023) / 1024;

  // Workspace (~96.4 MB):
  //   packed2[E] (64MB) | binStart2[64K ints] | s0[N] | X[N]f32x4 | G[3*GP]
  // Build aliases (over s0/X/G, dead until build done):
  //   histB[MA] | histT[MA] | scanT[MA] | partial[1024] | packed1C[6.5M]
  unsigned int* packed2 = (unsigned int*)d_ws;
  int* binStart2 = (int*)(packed2 + (size_t)E);       // NBKT*512+1 used
  float* s0 = (float*)(binStart2 + 65536);
  f32x4* X = (f32x4*)(s0 + (size_t)N);
  float* G = (float*)(X + (size_t)N);
  float* G0 = G, *G1 = G + GP, *G2 = G + 2 * (size_t)GP;
  int* histB = (int*)s0;                 // build-phase only
  int* histT = histB + MA;
  int* scanT = histT + MA;
  int* partial = scanT + MA;
  unsigned int* packed1C = (unsigned int*)(partial + 1024);

  // --- Build phase A: hist + scan (bucket x src-superblock, 984 bins) ---
  k_zeroi<<<512, 1024, 0, stream>>>(histB, MA);
  k_phist<<<NBLK, BT, 0, stream>>>(src, dst, histB, E, chunk);
  {
    dim3 g1(NBINS_A / 64, NBLK / 64);  // histB[256][1024] -> histT[1024][256]
    k_transp<<<g1, BT, 0, stream>>>(histB, histT, NBLK, NBINS_A);
  }
  k_blockSum<<<MA / BT, BT, 0, stream>>>(histT, partial, MA);
  k_scanPartials<<<1, BT, 0, stream>>>(partial, MA / BT);
  k_scanFinal<<<MA / BT, BT, 0, stream>>>(histT, partial, MA);
  {
    dim3 g2(NBLK / 64, NBINS_A / 64);  // -> scanT[256][1024]; row 0 = bin starts
    k_transp<<<g2, BT, 0, stream>>>(histT, scanT, NBINS_A, NBLK);
  }
  // --- Chunked scatter + refine (packed1C <= ~5.4M edges per chunk) ---
  {
    const int kLos[4] = {0, 41, 82, 123};
    for (int c = 0; c < 3; ++c) {
      int kLo = kLos[c], kHi = kLos[c + 1];
      k_pscatterC<<<NBLK, BT, 0, stream>>>(src, dst, scanT, packed1C, E, chunk, kLo, kHi);
      k_refine<<<kHi - kLo, 1024, 0, stream>>>(scanT, packed1C, packed2, binStart2, kLo, E);
    }
  }
  // --- Zero G planes, compute s0 (after aliases are dead) ---
  k_zeroi<<<1024, 1024, 0, stream>>>((int*)G, 3 * GP);
  k_init<<<(N + BT - 1) / BT, BT, 0, stream>>>(feat, norm, s0, N);

  const int gPass = NBKT * 2;  // 246

  // --- Layer 1 (1ch in) ---
  k_pass1<<<gPass, 1024, 0, stream>>>(binStart2, packed2, s0, G0, N);
  k_epi1<<<nbE, 1024, 0, stream>>>(G0, norm, W1, b1, X, N);
  // --- Layers 2-4 (3ch) ---
  k_pass3<<<gPass, 1024, 0, stream>>>(binStart2, packed2, X, G0, G1, G2, N);
  k_epi3<<<nbE, 1024, 0, stream>>>(G0, G1, G2, norm, W2, b2, X, N);
  k_pass3<<<gPass, 1024, 0, stream>>>(binStart2, packed2, X, G0, G1, G2, N);
  k_epi3<<<nbE, 1024, 0, stream>>>(G0, G1, G2, norm, W3, b3, X, N);
  k_pass3<<<gPass, 1024, 0, stream>>>(binStart2, packed2, X, G0, G1, G2, N);
  k_epi3<<<nbE, 1024, 0, stream>>>(G0, G1, G2, norm, W4, b4, X, N);
  // --- Layer 5 (3ch, W6 folded) -> sB in s0 buffer ---
  k_pass3<<<gPass, 1024, 0, stream>>>(binStart2, packed2, X, G0, G1, G2, N);
  k_epi5<<<nbE, 1024, 0, stream>>>(G0, G1, G2, norm, W5, b5, W6, s0, N);
  // --- Layer 6 (1ch) ---
  k_pass1<<<gPass, 1024, 0, stream>>>(binStart2, packed2, s0, G0, N);
  k_epi6<<<nbE, 1024, 0, stream>>>(G0, norm, b6, out, N);
}

// Round 8
// 2568.707 us; speedup vs baseline: 1.4990x; 1.2573x over previous
//
#include <hip/hip_runtime.h>

// ---------------------------------------------------------------------------
// GCN, 6 layers, N=1M nodes, E=16M edges.
// R13: R12's pure-LDS pass was right but serially scheduled: 4.8K cy/window
// (binStart load -> nt packed load (HBM!) -> atomics -> 2 bars -> X wait, all
// dependent, x245 windows = 491us with VALU 8.7% and FETCH 68MB). Fix the
// SCHEDULE, keep the verified structure: software-pipeline windows -- next
// window's binStarts + packed word + X data all prefetched into registers
// during the current window; edge phase touches only regs+LDS. nt dropped
// from packed (it forced 900cy HBM latency). pass1 reworked to 8192-node
// stage windows (62 steps, 4 bins/step via 3 compares). Build: phase-A
// scatter runs ONCE (R9-verified LDS-cursor shape) into the packed2 buffer;
// chunks become span-copy + in-place refine (kills 2 full 128MB re-reads).
// Predict: k_pass3 491->100-160us, k_pass1 30-60us, total ~1000-1250us.
// packed1 = (src&0x1FFFF)<<13 | dst13 (sb from bin). packed2 =
// (src&2047)<<13 | dst13; binStart2[(k<<9)+w], w = window-of-2048 in bucket.
// ---------------------------------------------------------------------------

#define BT 256            // build-kernel block size
#define NBLK 256          // partition blocks (phase A)
#define NBINS_A 1024      // (dst>>13)<<3 | (src>>17); real 123*8=984
#define MA (NBLK * NBINS_A)  // 262144
#define NBKT 123          // dst buckets of 8192
#define BSHIFT 13
#define DMASK 8191
#define WSHIFT 11         // 2048-node src windows
#define SMASK 2047
#define NW 489            // ceil(1e6/2048)
#define NWH 245           // window split point
#define GP 1007616        // padded G plane length = NBKT*8192

typedef float __attribute__((ext_vector_type(4))) f32x4;

__device__ __forceinline__ int keyA(int s, int d) {
  return (int)((((unsigned)d >> BSHIFT) << 3) | ((unsigned)s >> 17));
}

// s0 = feat * norm
__global__ void k_init(const float* __restrict__ feat, const float* __restrict__ norm,
                       float* __restrict__ s0, int N) {
  int i = blockIdx.x * BT + threadIdx.x;
  if (i < N) s0[i] = feat[i] * norm[i];
}

// generic zero (grid-stride)
__global__ void k_zeroi(int* __restrict__ p, int n) {
  for (int i = blockIdx.x * blockDim.x + threadIdx.x; i < n; i += gridDim.x * blockDim.x)
    p[i] = 0;
}

// Phase A P1: per-block LDS histogram of (bucket, src_sb) bins
__global__ void k_phist(const int* __restrict__ src, const int* __restrict__ dst,
                        int* __restrict__ histB, int E, int chunk) {
  __shared__ int h[NBINS_A];
  for (int i = threadIdx.x; i < NBINS_A; i += BT) h[i] = 0;
  __syncthreads();
  int b = blockIdx.x;
  int beg = b * chunk, end = min(beg + chunk, E);
  int i = beg + (int)threadIdx.x * 4;  // beg 16B-aligned (chunk % 4 == 0)
  for (; i + 3 < end; i += BT * 4) {
    int4 u = *(const int4*)(src + i);
    int4 v = *(const int4*)(dst + i);
    atomicAdd(&h[keyA(u.x, v.x)], 1);
    atomicAdd(&h[keyA(u.y, v.y)], 1);
    atomicAdd(&h[keyA(u.z, v.z)], 1);
    atomicAdd(&h[keyA(u.w, v.w)], 1);
  }
  for (; i < end; ++i) atomicAdd(&h[keyA(src[i], dst[i])], 1);
  __syncthreads();
  for (int k = threadIdx.x; k < NBINS_A; k += BT) histB[b * NBINS_A + k] = h[k];
}

// Tiled transpose: in[R][C] -> out[C][R]. R,C multiples of 64. grid(C/64,R/64)
__global__ void k_transp(const int* __restrict__ in, int* __restrict__ out, int R, int C) {
  __shared__ int tile[64][65];
  int c0 = blockIdx.x * 64, r0 = blockIdx.y * 64;
  int tx = threadIdx.x & 63, ty = threadIdx.x >> 6;  // 64 x 4
  for (int j = 0; j < 16; ++j) {
    int r = ty + j * 4;
    tile[r][tx] = in[(size_t)(r0 + r) * C + c0 + tx];
  }
  __syncthreads();
  for (int j = 0; j < 16; ++j) {
    int r = ty + j * 4;
    out[(size_t)(c0 + r) * R + r0 + tx] = tile[tx][r];
  }
}

// scan A: per-block sums
__global__ void k_blockSum(const int* __restrict__ data, int* __restrict__ partial, int Mlen) {
  __shared__ int tmp[BT];
  int i = blockIdx.x * BT + threadIdx.x;
  tmp[threadIdx.x] = (i < Mlen) ? data[i] : 0;
  __syncthreads();
  for (int off = BT / 2; off > 0; off >>= 1) {
    if (threadIdx.x < off) tmp[threadIdx.x] += tmp[threadIdx.x + off];
    __syncthreads();
  }
  if (threadIdx.x == 0) partial[blockIdx.x] = tmp[0];
}

// scan B: exclusive scan of partials in place (single block)
__global__ void k_scanPartials(int* __restrict__ partial, int nb) {
  __shared__ int tmp[BT];
  __shared__ int carry;
  int t = threadIdx.x;
  if (t == 0) carry = 0;
  __syncthreads();
  for (int base = 0; base < nb; base += BT) {
    int i = base + t;
    int v = (i < nb) ? partial[i] : 0;
    tmp[t] = v;
    __syncthreads();
    for (int off = 1; off < BT; off <<= 1) {
      int x = 0;
      if (t >= off) x = tmp[t - off];
      __syncthreads();
      tmp[t] += x;
      __syncthreads();
    }
    if (i < nb) partial[i] = tmp[t] - v + carry;
    __syncthreads();
    if (t == BT - 1) carry += tmp[BT - 1];
    __syncthreads();
  }
}

// scan C: final exclusive scan in place
__global__ void k_scanFinal(int* __restrict__ data, const int* __restrict__ partial, int Mlen) {
  __shared__ int tmp[BT];
  int t = threadIdx.x;
  int i = blockIdx.x * BT + t;
  int v = (i < Mlen) ? data[i] : 0;
  tmp[t] = v;
  __syncthreads();
  for (int off = 1; off < BT; off <<= 1) {
    int x = 0;
    if (t >= off) x = tmp[t - off];
    __syncthreads();
    tmp[t] += x;
    __syncthreads();
  }
  if (i < Mlen) data[i] = tmp[t] - v + partial[blockIdx.x];
}

// Phase A P2: single full scatter of packed1 into the packed2 buffer,
// per-block LDS cursors (R9-verified shape; 984 real bins, ~252K streams).
__global__ void k_pscatterA(const int* __restrict__ src, const int* __restrict__ dst,
                            const int* __restrict__ scanT, unsigned int* __restrict__ p1out,
                            int E, int chunk) {
  __shared__ int cur[NBINS_A];
  int b = blockIdx.x;
  for (int k = threadIdx.x; k < NBINS_A; k += BT) cur[k] = scanT[b * NBINS_A + k];
  __syncthreads();
  int beg = b * chunk, end = min(beg + chunk, E);
#define SCAT1(S, D)                                                         \
  {                                                                         \
    int pos = atomicAdd(&cur[keyA(S, D)], 1);                               \
    p1out[pos] =                                                            \
        (((unsigned)(S) & 0x1FFFFu) << BSHIFT) | ((unsigned)(D) & DMASK);   \
  }
  int i = beg + (int)threadIdx.x * 4;
  for (; i + 3 < end; i += BT * 4) {
    int4 u = *(const int4*)(src + i);
    int4 v = *(const int4*)(dst + i);
    SCAT1(u.x, v.x) SCAT1(u.y, v.y) SCAT1(u.z, v.z) SCAT1(u.w, v.w)
  }
  for (; i < end; ++i) SCAT1(src[i], dst[i]);
#undef SCAT1
}

// copy bucket-chunk span of packed1 out of the packed2 buffer (for in-place refine)
__global__ void k_copy(const int* __restrict__ scanT, const unsigned int* __restrict__ in,
                       unsigned int* __restrict__ out, int kLo, int kHi) {
  int beg = scanT[kLo << 3], end = scanT[kHi << 3];
  for (int i = beg + (int)(blockIdx.x * 1024 + threadIdx.x); i < end; i += gridDim.x * 1024)
    out[i - beg] = in[i];
}

// Phase B: per-bucket refine to 2048-node windows. One block per bucket.
// w = sb*64 + (srcInSb>>11); scatter into the bucket's own (L2-resident) range.
__global__ __launch_bounds__(1024) void k_refine(
    const int* __restrict__ bA, const unsigned int* __restrict__ packed1C,
    unsigned int* __restrict__ packed2, int* __restrict__ binStart2,
    int kLo, int E) {
  __shared__ int hist[512], sc[512], cur[512];
  int t = threadIdx.x;
  int k = kLo + blockIdx.x;
  int chunkBase = bA[kLo << 3];
  if (t < 512) hist[t] = 0;
  __syncthreads();
  for (int sb = 0; sb < 8; ++sb) {
    int lo = bA[(k << 3) + sb], hi = bA[(k << 3) + sb + 1];
    for (int i = lo + t; i < hi; i += 1024) {
      unsigned p = packed1C[i - chunkBase];
      atomicAdd(&hist[(sb << 6) | (p >> 24)], 1);
    }
  }
  __syncthreads();
  if (t < 512) sc[t] = hist[t];
  __syncthreads();
  for (int off = 1; off < 512; off <<= 1) {
    int v = 0;
    if (t >= off && t < 512) v = sc[t - off];
    __syncthreads();
    if (t < 512) sc[t] += v;
    __syncthreads();
  }
  int bucketBase = bA[k << 3];
  if (t < 512) {
    int ex = bucketBase + sc[t] - hist[t];  // exclusive scan + global base
    cur[t] = ex;
    binStart2[(k << 9) + t] = ex;
  }
  if (k == NBKT - 1 && t == 0) binStart2[NBKT << 9] = E;
  __syncthreads();
  for (int sb = 0; sb < 8; ++sb) {
    int lo = bA[(k << 3) + sb], hi = bA[(k << 3) + sb + 1];
    for (int i = lo + t; i < hi; i += 1024) {
      unsigned p = packed1C[i - chunkBase];
      int w = (sb << 6) | (int)(p >> 24);
      int pos = atomicAdd(&cur[w], 1);
      packed2[pos] = (((p >> BSHIFT) & SMASK) << BSHIFT) | (p & DMASK);
    }
  }
}

// --- 3-channel pass, software-pipelined windows.
// During window w: prefetch X(w+1) + binStarts(w+1) + packed(w+1) into regs;
// edge phase touches only regs + LDS. Per-window serial = stage-store wait +
// 2 barriers (latencies hidden one full window ahead).
__global__ __launch_bounds__(1024) void k_pass3(
    const int* __restrict__ binStart2, const unsigned int* __restrict__ packed,
    const f32x4* __restrict__ X, float* __restrict__ G0, float* __restrict__ G1,
    float* __restrict__ G2, int N) {
  __shared__ f32x4 stage[2048];                   // 32 KB
  __shared__ float a0[8192], a1[8192], a2[8192];  // 96 KB
  int t = threadIdx.x;
  int k = blockIdx.x >> 1, s = blockIdx.x & 1;
  for (int j = t; j < 8192; j += 1024) { a0[j] = 0.0f; a1[j] = 0.0f; a2[j] = 0.0f; }
  int wbeg = s ? NWH : 0, wend = s ? NW : NWH;
  int base = k << 9;
  f32x4 z = {0.0f, 0.0f, 0.0f, 0.0f};
  // prime: X, binStarts, packed word for wbeg
  f32x4 r0, r1;
  {
    int nb = wbeg << WSHIFT;
    int i0 = nb + t, i1 = i0 + 1024;
    r0 = (i0 < N) ? X[i0] : z;
    r1 = (i1 < N) ? X[i1] : z;
  }
  int beg = binStart2[base + wbeg], end = binStart2[base + wbeg + 1];
  unsigned pk = 0;
  if (beg + t < end) pk = packed[beg + t];
  stage[t] = r0;
  stage[t + 1024] = r1;
  __syncthreads();
  for (int w = wbeg; w < wend; ++w) {
    bool more = (w + 1 < wend);
    f32x4 n0 = z, n1 = z;
    int begN = 0, endN = 0;
    unsigned pkN = 0;
    if (more) {  // all prefetches for w+1: independent, issue early
      int nb = (w + 1) << WSHIFT;
      int i0 = nb + t, i1 = i0 + 1024;
      n0 = (i0 < N) ? X[i0] : z;
      n1 = (i1 < N) ? X[i1] : z;
      begN = binStart2[base + w + 1];
      endN = binStart2[base + w + 2];
      if (begN + t < endN) pkN = packed[begN + t];
    }
    // edge phase: regs + LDS only
    if (beg + t < end) {
      f32x4 m = stage[pk >> BSHIFT];
      int loc = pk & DMASK;
      atomicAdd(&a0[loc], m.x);
      atomicAdd(&a1[loc], m.y);
      atomicAdd(&a2[loc], m.z);
    }
    for (int i = beg + 1024 + t; i < end; i += 1024) {  // rare overflow (>1024 edges)
      unsigned p = packed[i];
      f32x4 m = stage[p >> BSHIFT];
      int loc = p & DMASK;
      atomicAdd(&a0[loc], m.x);
      atomicAdd(&a1[loc], m.y);
      atomicAdd(&a2[loc], m.z);
    }
    __syncthreads();  // reads of stage done
    if (more) { stage[t] = n0; stage[t + 1024] = n1; }
    __syncthreads();  // new stage visible
    beg = begN; end = endN; pk = pkN;
  }
  int gb = k << BSHIFT;
  for (int j = t; j < 8192; j += 1024) {
    atomicAdd(&G0[gb + j], a0[j]);
    atomicAdd(&G1[gb + j], a1[j]);
    atomicAdd(&G2[gb + j], a2[j]);
  }
}

// --- scalar pass: 8192-node stage windows (4 bins each, 62 steps), pipelined.
// Edge's src-in-stage = 2048*(#bin boundaries passed) + (p>>13).
__global__ __launch_bounds__(1024) void k_pass1(
    const int* __restrict__ binStart2, const unsigned int* __restrict__ packed,
    const float* __restrict__ sIn, float* __restrict__ G0, int N) {
  __shared__ float stage[8192];  // 32 KB
  __shared__ float a[8192];      // 32 KB
  int t = threadIdx.x;
  int k = blockIdx.x >> 1, s = blockIdx.x & 1;
  for (int j = t; j < 8192; j += 1024) a[j] = 0.0f;
  const int NW8 = 123;  // windows of 8192
  int wbeg = s ? 62 : 0, wend = s ? NW8 : 62;
  int base = k << 9;
  float r[8];
  {
    int nb = wbeg << 13;
#pragma unroll
    for (int j = 0; j < 8; ++j) {
      int idx = nb + t + (j << 10);
      r[j] = (idx < N) ? sIn[idx] : 0.0f;
    }
  }
  int q0 = base + (wbeg << 2);
  int b0 = binStart2[q0], b1 = binStart2[q0 + 1], b2 = binStart2[q0 + 2],
      b3 = binStart2[q0 + 3], b4 = binStart2[q0 + 4];
  unsigned pkA = 0, pkB = 0;
  if (b0 + t < b4) pkA = packed[b0 + t];
  if (b0 + 1024 + t < b4) pkB = packed[b0 + 1024 + t];
#pragma unroll
  for (int j = 0; j < 8; ++j) stage[t + (j << 10)] = r[j];
  __syncthreads();
  for (int w = wbeg; w < wend; ++w) {
    bool more = (w + 1 < wend);
    float n[8];
    int c0 = 0, c1 = 0, c2 = 0, c3 = 0, c4 = 0;
    unsigned qA = 0, qB = 0;
    if (more) {
      int nb = (w + 1) << 13;
#pragma unroll
      for (int j = 0; j < 8; ++j) {
        int idx = nb + t + (j << 10);
        n[j] = (idx < N) ? sIn[idx] : 0.0f;
      }
      int nq = base + ((w + 1) << 2);
      c0 = binStart2[nq]; c1 = binStart2[nq + 1]; c2 = binStart2[nq + 2];
      c3 = binStart2[nq + 3]; c4 = binStart2[nq + 4];
      if (c0 + t < c4) qA = packed[c0 + t];
      if (c0 + 1024 + t < c4) qB = packed[c0 + 1024 + t];
    }
    // edge phase
    {
      int i = b0 + t;
      if (i < b4) {
        int off = (i >= b1) + (i >= b2) + (i >= b3);
        atomicAdd(&a[pkA & DMASK], stage[(off << 11) + (int)(pkA >> BSHIFT)]);
      }
      int i2 = b0 + 1024 + t;
      if (i2 < b4) {
        int off = (i2 >= b1) + (i2 >= b2) + (i2 >= b3);
        atomicAdd(&a[pkB & DMASK], stage[(off << 11) + (int)(pkB >> BSHIFT)]);
      }
      for (int i3 = b0 + 2048 + t; i3 < b4; i3 += 1024) {  // rare overflow
        unsigned p = packed[i3];
        int off = (i3 >= b1) + (i3 >= b2) + (i3 >= b3);
        atomicAdd(&a[p & DMASK], stage[(off << 11) + (int)(p >> BSHIFT)]);
      }
    }
    __syncthreads();
    if (more) {
#pragma unroll
      for (int j = 0; j < 8; ++j) stage[t + (j << 10)] = n[j];
    }
    __syncthreads();
    b0 = c0; b1 = c1; b2 = c2; b3 = c3; b4 = c4; pkA = qA; pkB = qB;
  }
  int gb = k << BSHIFT;
  for (int j = t; j < 8192; j += 1024) atomicAdd(&G0[gb + j], a[j]);
}

// --- epilogues: norm/GEMV/ReLU; re-zero G planes for the next layer ---

__global__ void k_epi1(float* __restrict__ G0, const float* __restrict__ norm,
                       const float* __restrict__ W1, const float* __restrict__ b1,
                       f32x4* __restrict__ X, int N) {
  int i = blockIdx.x * 1024 + threadIdx.x;
  if (i >= N) return;
  float n = norm[i];
  float pre = G0[i] * n;
  G0[i] = 0.0f;
  f32x4 o = {fmaxf(0.0f, pre * W1[0] + b1[0]) * n, fmaxf(0.0f, pre * W1[1] + b1[1]) * n,
             fmaxf(0.0f, pre * W1[2] + b1[2]) * n, 0.0f};
  X[i] = o;
}

__global__ void k_epi3(float* __restrict__ G0, float* __restrict__ G1, float* __restrict__ G2,
                       const float* __restrict__ norm, const float* __restrict__ W,
                       const float* __restrict__ bias, f32x4* __restrict__ X, int N) {
  int i = blockIdx.x * 1024 + threadIdx.x;
  if (i >= N) return;
  float n = norm[i];
  float x0 = G0[i] * n, x1 = G1[i] * n, x2 = G2[i] * n;
  G0[i] = 0.0f; G1[i] = 0.0f; G2[i] = 0.0f;
  float h0 = fmaxf(0.0f, x0 * W[0] + x1 * W[3] + x2 * W[6] + bias[0]);
  float h1 = fmaxf(0.0f, x0 * W[1] + x1 * W[4] + x2 * W[7] + bias[1]);
  float h2 = fmaxf(0.0f, x0 * W[2] + x1 * W[5] + x2 * W[8] + bias[2]);
  f32x4 o = {h0 * n, h1 * n, h2 * n, 0.0f};
  X[i] = o;
}

__global__ void k_epi5(float* __restrict__ G0, float* __restrict__ G1, float* __restrict__ G2,
                       const float* __restrict__ norm, const float* __restrict__ W5,
                       const float* __restrict__ b5, const float* __restrict__ W6,
                       float* __restrict__ sB, int N) {
  int i = blockIdx.x * 1024 + threadIdx.x;
  if (i >= N) return;
  float n = norm[i];
  float x0 = G0[i] * n, x1 = G1[i] * n, x2 = G2[i] * n;
  G0[i] = 0.0f; G1[i] = 0.0f; G2[i] = 0.0f;
  float h0 = fmaxf(0.0f, x0 * W5[0] + x1 * W5[3] + x2 * W5[6] + b5[0]);
  float h1 = fmaxf(0.0f, x0 * W5[1] + x1 * W5[4] + x2 * W5[7] + b5[1]);
  float h2 = fmaxf(0.0f, x0 * W5[2] + x1 * W5[5] + x2 * W5[8] + b5[2]);
  sB[i] = (h0 * W6[0] + h1 * W6[1] + h2 * W6[2]) * n;
}

__global__ void k_epi6(const float* __restrict__ G0, const float* __restrict__ norm,
                       const float* __restrict__ b6, float* __restrict__ out, int N) {
  int i = blockIdx.x * 1024 + threadIdx.x;
  if (i >= N) return;
  out[i] = fmaxf(0.0f, G0[i] * norm[i] + b6[0]);
}

extern "C" void kernel_launch(void* const* d_in, const int* in_sizes, int n_in,
                              void* d_out, int out_size, void* d_ws, size_t ws_size,
                              hipStream_t stream) {
  const float* feat = (const float*)d_in[0];
  const float* norm = (const float*)d_in[1];
  const int* src = (const int*)d_in[2];
  const int* dst = (const int*)d_in[3];
  const float* W1 = (const float*)d_in[4];
  const float* b1 = (const float*)d_in[5];
  const float* W2 = (const float*)d_in[6];
  const float* b2 = (const float*)d_in[7];
  const float* W3 = (const float*)d_in[8];
  const float* b3 = (const float*)d_in[9];
  const float* W4 = (const float*)d_in[10];
  const float* b4 = (const float*)d_in[11];
  const float* W5 = (const float*)d_in[12];
  const float* b5 = (const float*)d_in[13];
  const float* W6 = (const float*)d_in[14];
  const float* b6 = (const float*)d_in[15];
  float* out = (float*)d_out;

  const int N = in_sizes[0];
  const int E = in_sizes[2];
  const int chunk = (((E + NBLK - 1) / NBLK) + 3) & ~3;  // 16B-aligned
  const int nbE = (N + 1023) / 1024;

  // Workspace (~96.4 MB):
  //   packed2[E] (64MB) | binStart2[64K ints] | s0[N] | X[N]f32x4 | G[3*GP]
  // Build aliases (over s0/X/G, dead until build done):
  //   histB[MA] | histT[MA] | scanT[MA] | partial[1024] | packed1C[<=7M]
  unsigned int* packed2 = (unsigned int*)d_ws;
  int* binStart2 = (int*)(packed2 + (size_t)E);
  float* s0 = (float*)(binStart2 + 65536);
  f32x4* X = (f32x4*)(s0 + (size_t)N);
  float* G = (float*)(X + (size_t)N);
  float* G0 = G, *G1 = G + GP, *G2 = G + 2 * (size_t)GP;
  int* histB = (int*)s0;  // build-phase only
  int* histT = histB + MA;
  int* scanT = histT + MA;
  int* partial = scanT + MA;
  unsigned int* packed1C = (unsigned int*)(partial + 1024);

  // --- Build phase A: hist + scan + ONE full scatter into packed2 buffer ---
  k_zeroi<<<512, 1024, 0, stream>>>(histB, MA);
  k_phist<<<NBLK, BT, 0, stream>>>(src, dst, histB, E, chunk);
  {
    dim3 g1(NBINS_A / 64, NBLK / 64);
    k_transp<<<g1, BT, 0, stream>>>(histB, histT, NBLK, NBINS_A);
  }
  k_blockSum<<<MA / BT, BT, 0, stream>>>(histT, partial, MA);
  k_scanPartials<<<1, BT, 0, stream>>>(partial, MA / BT);
  k_scanFinal<<<MA / BT, BT, 0, stream>>>(histT, partial, MA);
  {
    dim3 g2(NBLK / 64, NBINS_A / 64);  // -> scanT[256][1024]; row 0 = bin starts
    k_transp<<<g2, BT, 0, stream>>>(histT, scanT, NBINS_A, NBLK);
  }
  k_pscatterA<<<NBLK, BT, 0, stream>>>(src, dst, scanT, packed2, E, chunk);
  // --- Phase B: per-chunk span-copy + in-place refine ---
  {
    const int kLos[4] = {0, 41, 82, 123};
    for (int c = 0; c < 3; ++c) {
      int kLo = kLos[c], kHi = kLos[c + 1];
      k_copy<<<2048, 1024, 0, stream>>>(scanT, packed2, packed1C, kLo, kHi);
      k_refine<<<kHi - kLo, 1024, 0, stream>>>(scanT, packed1C, packed2, binStart2, kLo, E);
    }
  }
  // --- Zero G planes, compute s0 (after aliases are dead) ---
  k_zeroi<<<1024, 1024, 0, stream>>>((int*)G, 3 * GP);
  k_init<<<(N + BT - 1) / BT, BT, 0, stream>>>(feat, norm, s0, N);

  const int gPass = NBKT * 2;  // 246

  // --- Layer 1 (1ch in) ---
  k_pass1<<<gPass, 1024, 0, stream>>>(binStart2, packed2, s0, G0, N);
  k_epi1<<<nbE, 1024, 0, stream>>>(G0, norm, W1, b1, X, N);
  // --- Layers 2-4 (3ch) ---
  k_pass3<<<gPass, 1024, 0, stream>>>(binStart2, packed2, X, G0, G1, G2, N);
  k_epi3<<<nbE, 1024, 0, stream>>>(G0, G1, G2, norm, W2, b2, X, N);
  k_pass3<<<gPass, 1024, 0, stream>>>(binStart2, packed2, X, G0, G1, G2, N);
  k_epi3<<<nbE, 1024, 0, stream>>>(G0, G1, G2, norm, W3, b3, X, N);
  k_pass3<<<gPass, 1024, 0, stream>>>(binStart2, packed2, X, G0, G1, G2, N);
  k_epi3<<<nbE, 1024, 0, stream>>>(G0, G1, G2, norm, W4, b4, X, N);
  // --- Layer 5 (3ch, W6 folded) -> sB in s0 buffer ---
  k_pass3<<<gPass, 1024, 0, stream>>>(binStart2, packed2, X, G0, G1, G2, N);
  k_epi5<<<nbE, 1024, 0, stream>>>(G0, G1, G2, norm, W5, b5, W6, s0, N);
  // --- Layer 6 (1ch) ---
  k_pass1<<<gPass, 1024, 0, stream>>>(binStart2, packed2, s0, G0, N);
  k_epi6<<<nbE, 1024, 0, stream>>>(G0, norm, b6, out, N);
}

// Round 9
// 2413.735 us; speedup vs baseline: 1.5953x; 1.0642x over previous
//
#include <hip/hip_runtime.h>

// ---------------------------------------------------------------------------
// GCN, 6 layers, N=1M nodes, E=16M edges.
// R14: R13's pass3 = 3.8K cy/window x 245 windows, all overhead (edge phase
// ~0.26 edges/thread): binStart->packed dependent chain + stage-load latency
// exposed every window + 2 barriers. Fix: (1) chain-free packed prefetch via
// clamp (packed[min(c2+t,E-1)] -- base known from last iter, validity checked
// at use); (2) depth-2 stage pipeline (stage regs for w+1 COMPLETE when
// ds_written; w+2 issued at window top); (3) X as 3 planes (SoA) -> stage
// 4096 nodes = 48KB + acc 96KB = 144KB LDS, 123 windows/block (was 245);
// window parity from bin index, so build (verified R12/R13) is UNTOUCHED.
// pass1 same treatment (8192-node windows, 4 bins/step). Direct-design cost
// model (R0-R10 fit): each random gather = 128B L1-line fill from L2 ->
// ~2GB/layer at ~8TB/s random-line rate; LDS design avoids that class.
// Predict: pass3 389->150-210us, pass1 ->50-80us, total 2569->~1500-1650.
// packed1 = (src&0x1FFFF)<<13 | dst13. packed2 = (src&2047)<<13 | dst13.
// binStart2[(k<<9)+w]: k = 8192-dst bucket, w = 2048-src window.
// ---------------------------------------------------------------------------

#define BT 256            // build-kernel block size
#define NBLK 256          // partition blocks (phase A)
#define NBINS_A 1024      // (dst>>13)<<3 | (src>>17); real 123*8=984
#define MA (NBLK * NBINS_A)  // 262144
#define NBKT 123          // dst buckets of 8192
#define BSHIFT 13
#define DMASK 8191
#define GP 1007616        // padded G plane length = NBKT*8192

typedef float __attribute__((ext_vector_type(4))) f32x4;

__device__ __forceinline__ int keyA(int s, int d) {
  return (int)((((unsigned)d >> BSHIFT) << 3) | ((unsigned)s >> 17));
}

// guarded 16B plane load
__device__ __forceinline__ f32x4 ldg4(const float* __restrict__ P, int nb, int t, int N) {
  int off = nb + (t << 2);
  if (off + 3 < N) return *(const f32x4*)(P + off);
  f32x4 v = {0.0f, 0.0f, 0.0f, 0.0f};
  if (off < N) v.x = P[off];
  if (off + 1 < N) v.y = P[off + 1];
  if (off + 2 < N) v.z = P[off + 2];
  return v;
}

// s0 = feat * norm
__global__ void k_init(const float* __restrict__ feat, const float* __restrict__ norm,
                       float* __restrict__ s0, int N) {
  int i = blockIdx.x * BT + threadIdx.x;
  if (i < N) s0[i] = feat[i] * norm[i];
}

// generic zero (grid-stride)
__global__ void k_zeroi(int* __restrict__ p, int n) {
  for (int i = blockIdx.x * blockDim.x + threadIdx.x; i < n; i += gridDim.x * blockDim.x)
    p[i] = 0;
}

// Phase A P1: per-block LDS histogram of (bucket, src_sb) bins
__global__ void k_phist(const int* __restrict__ src, const int* __restrict__ dst,
                        int* __restrict__ histB, int E, int chunk) {
  __shared__ int h[NBINS_A];
  for (int i = threadIdx.x; i < NBINS_A; i += BT) h[i] = 0;
  __syncthreads();
  int b = blockIdx.x;
  int beg = b * chunk, end = min(beg + chunk, E);
  int i = beg + (int)threadIdx.x * 4;  // beg 16B-aligned (chunk % 4 == 0)
  for (; i + 3 < end; i += BT * 4) {
    int4 u = *(const int4*)(src + i);
    int4 v = *(const int4*)(dst + i);
    atomicAdd(&h[keyA(u.x, v.x)], 1);
    atomicAdd(&h[keyA(u.y, v.y)], 1);
    atomicAdd(&h[keyA(u.z, v.z)], 1);
    atomicAdd(&h[keyA(u.w, v.w)], 1);
  }
  for (; i < end; ++i) atomicAdd(&h[keyA(src[i], dst[i])], 1);
  __syncthreads();
  for (int k = threadIdx.x; k < NBINS_A; k += BT) histB[b * NBINS_A + k] = h[k];
}

// Tiled transpose: in[R][C] -> out[C][R]. R,C multiples of 64. grid(C/64,R/64)
__global__ void k_transp(const int* __restrict__ in, int* __restrict__ out, int R, int C) {
  __shared__ int tile[64][65];
  int c0 = blockIdx.x * 64, r0 = blockIdx.y * 64;
  int tx = threadIdx.x & 63, ty = threadIdx.x >> 6;  // 64 x 4
  for (int j = 0; j < 16; ++j) {
    int r = ty + j * 4;
    tile[r][tx] = in[(size_t)(r0 + r) * C + c0 + tx];
  }
  __syncthreads();
  for (int j = 0; j < 16; ++j) {
    int r = ty + j * 4;
    out[(size_t)(c0 + r) * R + r0 + tx] = tile[tx][r];
  }
}

// scan A: per-block sums
__global__ void k_blockSum(const int* __restrict__ data, int* __restrict__ partial, int Mlen) {
  __shared__ int tmp[BT];
  int i = blockIdx.x * BT + threadIdx.x;
  tmp[threadIdx.x] = (i < Mlen) ? data[i] : 0;
  __syncthreads();
  for (int off = BT / 2; off > 0; off >>= 1) {
    if (threadIdx.x < off) tmp[threadIdx.x] += tmp[threadIdx.x + off];
    __syncthreads();
  }
  if (threadIdx.x == 0) partial[blockIdx.x] = tmp[0];
}

// scan B: exclusive scan of partials in place (single block)
__global__ void k_scanPartials(int* __restrict__ partial, int nb) {
  __shared__ int tmp[BT];
  __shared__ int carry;
  int t = threadIdx.x;
  if (t == 0) carry = 0;
  __syncthreads();
  for (int base = 0; base < nb; base += BT) {
    int i = base + t;
    int v = (i < nb) ? partial[i] : 0;
    tmp[t] = v;
    __syncthreads();
    for (int off = 1; off < BT; off <<= 1) {
      int x = 0;
      if (t >= off) x = tmp[t - off];
      __syncthreads();
      tmp[t] += x;
      __syncthreads();
    }
    if (i < nb) partial[i] = tmp[t] - v + carry;
    __syncthreads();
    if (t == BT - 1) carry += tmp[BT - 1];
    __syncthreads();
  }
}

// scan C: final exclusive scan in place
__global__ void k_scanFinal(int* __restrict__ data, const int* __restrict__ partial, int Mlen) {
  __shared__ int tmp[BT];
  int t = threadIdx.x;
  int i = blockIdx.x * BT + t;
  int v = (i < Mlen) ? data[i] : 0;
  tmp[t] = v;
  __syncthreads();
  for (int off = 1; off < BT; off <<= 1) {
    int x = 0;
    if (t >= off) x = tmp[t - off];
    __syncthreads();
    tmp[t] += x;
    __syncthreads();
  }
  if (i < Mlen) data[i] = tmp[t] - v + partial[blockIdx.x];
}

// Phase A P2: single full scatter of packed1 into the packed2 buffer,
// per-block LDS cursors (R9-verified shape; 984 real bins).
__global__ void k_pscatterA(const int* __restrict__ src, const int* __restrict__ dst,
                            const int* __restrict__ scanT, unsigned int* __restrict__ p1out,
                            int E, int chunk) {
  __shared__ int cur[NBINS_A];
  int b = blockIdx.x;
  for (int k = threadIdx.x; k < NBINS_A; k += BT) cur[k] = scanT[b * NBINS_A + k];
  __syncthreads();
  int beg = b * chunk, end = min(beg + chunk, E);
#define SCAT1(S, D)                                                         \
  {                                                                         \
    int pos = atomicAdd(&cur[keyA(S, D)], 1);                               \
    p1out[pos] =                                                            \
        (((unsigned)(S) & 0x1FFFFu) << BSHIFT) | ((unsigned)(D) & DMASK);   \
  }
  int i = beg + (int)threadIdx.x * 4;
  for (; i + 3 < end; i += BT * 4) {
    int4 u = *(const int4*)(src + i);
    int4 v = *(const int4*)(dst + i);
    SCAT1(u.x, v.x) SCAT1(u.y, v.y) SCAT1(u.z, v.z) SCAT1(u.w, v.w)
  }
  for (; i < end; ++i) SCAT1(src[i], dst[i]);
#undef SCAT1
}

// copy bucket-chunk span of packed1 out of the packed2 buffer
__global__ void k_copy(const int* __restrict__ scanT, const unsigned int* __restrict__ in,
                       unsigned int* __restrict__ out, int kLo, int kHi) {
  int beg = scanT[kLo << 3], end = scanT[kHi << 3];
  for (int i = beg + (int)(blockIdx.x * 1024 + threadIdx.x); i < end; i += gridDim.x * 1024)
    out[i - beg] = in[i];
}

// Phase B: per-bucket refine to 2048-node windows. One block per bucket.
__global__ __launch_bounds__(1024) void k_refine(
    const int* __restrict__ bA, const unsigned int* __restrict__ packed1C,
    unsigned int* __restrict__ packed2, int* __restrict__ binStart2,
    int kLo, int E) {
  __shared__ int hist[512], sc[512], cur[512];
  int t = threadIdx.x;
  int k = kLo + blockIdx.x;
  int chunkBase = bA[kLo << 3];
  if (t < 512) hist[t] = 0;
  __syncthreads();
  for (int sb = 0; sb < 8; ++sb) {
    int lo = bA[(k << 3) + sb], hi = bA[(k << 3) + sb + 1];
    for (int i = lo + t; i < hi; i += 1024) {
      unsigned p = packed1C[i - chunkBase];
      atomicAdd(&hist[(sb << 6) | (p >> 24)], 1);
    }
  }
  __syncthreads();
  if (t < 512) sc[t] = hist[t];
  __syncthreads();
  for (int off = 1; off < 512; off <<= 1) {
    int v = 0;
    if (t >= off && t < 512) v = sc[t - off];
    __syncthreads();
    if (t < 512) sc[t] += v;
    __syncthreads();
  }
  int bucketBase = bA[k << 3];
  if (t < 512) {
    int ex = bucketBase + sc[t] - hist[t];  // exclusive scan + global base
    cur[t] = ex;
    binStart2[(k << 9) + t] = ex;
  }
  if (k == NBKT - 1 && t == 0) binStart2[NBKT << 9] = E;
  __syncthreads();
  for (int sb = 0; sb < 8; ++sb) {
    int lo = bA[(k << 3) + sb], hi = bA[(k << 3) + sb + 1];
    for (int i = lo + t; i < hi; i += 1024) {
      unsigned p = packed1C[i - chunkBase];
      int w = (sb << 6) | (int)(p >> 24);
      int pos = atomicAdd(&cur[w], 1);
      packed2[pos] = (((p >> BSHIFT) & 2047u) << BSHIFT) | (p & DMASK);
    }
  }
}

// --- 3-channel pass, chain-free depth-2 pipeline ---
// Window = 4096 src nodes (2 bins). SoA stage 48KB + acc 96KB = 144KB LDS.
// All global loads for window w+1/w+2 issued >=1 full window before use.
__global__ __launch_bounds__(1024) void k_pass3(
    const int* __restrict__ bs, const unsigned int* __restrict__ packed,
    const float* __restrict__ X0, const float* __restrict__ X1,
    const float* __restrict__ X2, float* __restrict__ G0, float* __restrict__ G1,
    float* __restrict__ G2, int N, int E) {
  __shared__ __align__(16) float sg0[4096], sg1[4096], sg2[4096];
  __shared__ float a0[8192], a1[8192], a2[8192];
  int t = threadIdx.x;
  int k = blockIdx.x >> 1, s = blockIdx.x & 1;
  for (int j = t; j < 8192; j += 1024) { a0[j] = 0.0f; a1[j] = 0.0f; a2[j] = 0.0f; }
  int wbeg = s ? 123 : 0, wend = s ? 245 : 123;  // windows of 4096 (245 total)
  int base = k << 9;
  int c0 = bs[base + 2 * wbeg],     c1 = bs[base + 2 * wbeg + 1],
      c2 = bs[base + 2 * wbeg + 2], c3 = bs[base + 2 * wbeg + 3],
      c4 = bs[base + 2 * wbeg + 4];
  unsigned pk = packed[min(c0 + t, E - 1)];
  {  // stage for wbeg
    int nb = wbeg << 12;
    f32x4 r0 = ldg4(X0, nb, t, N), r1 = ldg4(X1, nb, t, N), r2 = ldg4(X2, nb, t, N);
    *(f32x4*)&sg0[t << 2] = r0;
    *(f32x4*)&sg1[t << 2] = r1;
    *(f32x4*)&sg2[t << 2] = r2;
  }
  f32x4 u0, u1, u2;  // stage data for w+1 (in flight / complete)
  if (wbeg + 1 < wend) {
    int nb = (wbeg + 1) << 12;
    u0 = ldg4(X0, nb, t, N); u1 = ldg4(X1, nb, t, N); u2 = ldg4(X2, nb, t, N);
  }
  __syncthreads();
  for (int w = wbeg; w < wend; ++w) {
    bool more = (w + 1 < wend);
    f32x4 v0, v1, v2;  // issue stage loads for w+2
    if (w + 2 < wend) {
      int nb = (w + 2) << 12;
      v0 = ldg4(X0, nb, t, N); v1 = ldg4(X1, nb, t, N); v2 = ldg4(X2, nb, t, N);
    }
    unsigned pkN = 0;
    int b5 = 0, b6 = 0;
    if (more) {
      pkN = packed[min(c2 + t, E - 1)];  // base known: no chain
      b5 = bs[base + 2 * w + 5];
      b6 = bs[base + 2 * w + 6];
    }
    // edge phase: regs + LDS only
    if (c0 + t < c2) {
      int sidx = ((c0 + t >= c1) ? 2048 : 0) + (int)(pk >> BSHIFT);
      int loc = (int)(pk & DMASK);
      atomicAdd(&a0[loc], sg0[sidx]);
      atomicAdd(&a1[loc], sg1[sidx]);
      atomicAdd(&a2[loc], sg2[sidx]);
    }
    for (int i = c0 + 1024 + t; i < c2; i += 1024) {  // rare overflow
      unsigned p = packed[i];
      int sidx = ((i >= c1) ? 2048 : 0) + (int)(p >> BSHIFT);
      int loc = (int)(p & DMASK);
      atomicAdd(&a0[loc], sg0[sidx]);
      atomicAdd(&a1[loc], sg1[sidx]);
      atomicAdd(&a2[loc], sg2[sidx]);
    }
    __syncthreads();
    if (more) {  // u* completed a full window ago: no wait
      *(f32x4*)&sg0[t << 2] = u0;
      *(f32x4*)&sg1[t << 2] = u1;
      *(f32x4*)&sg2[t << 2] = u2;
    }
    __syncthreads();
    u0 = v0; u1 = v1; u2 = v2;
    c0 = c2; c1 = c3; c2 = c4; c3 = b5; c4 = b6;
    pk = pkN;
  }
  int gb = k << BSHIFT;
  for (int j = t; j < 8192; j += 1024) {
    atomicAdd(&G0[gb + j], a0[j]);
    atomicAdd(&G1[gb + j], a1[j]);
    atomicAdd(&G2[gb + j], a2[j]);
  }
}

// --- scalar pass: 8192-node windows (4 bins), same chain-free depth-2 pipeline
__global__ __launch_bounds__(1024) void k_pass1(
    const int* __restrict__ bs, const unsigned int* __restrict__ packed,
    const float* __restrict__ sIn, float* __restrict__ G0, int N, int E) {
  __shared__ __align__(16) float sg[8192];
  __shared__ float a[8192];
  int t = threadIdx.x;
  int k = blockIdx.x >> 1, s = blockIdx.x & 1;
  for (int j = t; j < 8192; j += 1024) a[j] = 0.0f;
  int wbeg = s ? 62 : 0, wend = s ? 123 : 62;  // windows of 8192 (123 total)
  int base = k << 9;
  int c0 = bs[base + 4 * wbeg],     c1 = bs[base + 4 * wbeg + 1],
      c2 = bs[base + 4 * wbeg + 2], c3 = bs[base + 4 * wbeg + 3],
      c4 = bs[base + 4 * wbeg + 4];
  unsigned pkA = packed[min(c0 + t, E - 1)];
  unsigned pkB = packed[min(c0 + 1024 + t, E - 1)];
  {
    int nb = wbeg << 13;
    f32x4 r0 = ldg4(sIn, nb, t, N), r1 = ldg4(sIn, nb + 4096, t, N);
    *(f32x4*)&sg[t << 2] = r0;
    *(f32x4*)&sg[4096 + (t << 2)] = r1;
  }
  f32x4 u0, u1;
  if (wbeg + 1 < wend) {
    int nb = (wbeg + 1) << 13;
    u0 = ldg4(sIn, nb, t, N); u1 = ldg4(sIn, nb + 4096, t, N);
  }
  __syncthreads();
  for (int w = wbeg; w < wend; ++w) {
    bool more = (w + 1 < wend);
    f32x4 v0, v1;
    if (w + 2 < wend) {
      int nb = (w + 2) << 13;
      v0 = ldg4(sIn, nb, t, N); v1 = ldg4(sIn, nb + 4096, t, N);
    }
    unsigned qA = 0, qB = 0;
    int d1 = 0, d2 = 0, d3 = 0, d4 = 0;
    if (more) {
      qA = packed[min(c4 + t, E - 1)];
      qB = packed[min(c4 + 1024 + t, E - 1)];
      d1 = bs[base + 4 * w + 5]; d2 = bs[base + 4 * w + 6];
      d3 = bs[base + 4 * w + 7]; d4 = bs[base + 4 * w + 8];
    }
    // edge phase
    {
      int i = c0 + t;
      if (i < c4) {
        int off = (i >= c1) + (i >= c2) + (i >= c3);
        atomicAdd(&a[pkA & DMASK], sg[(off << 11) + (int)(pkA >> BSHIFT)]);
      }
      int i2 = c0 + 1024 + t;
      if (i2 < c4) {
        int off = (i2 >= c1) + (i2 >= c2) + (i2 >= c3);
        atomicAdd(&a[pkB & DMASK], sg[(off << 11) + (int)(pkB >> BSHIFT)]);
      }
      for (int i3 = c0 + 2048 + t; i3 < c4; i3 += 1024) {  // rare overflow
        unsigned p = packed[i3];
        int off = (i3 >= c1) + (i3 >= c2) + (i3 >= c3);
        atomicAdd(&a[p & DMASK], sg[(off << 11) + (int)(p >> BSHIFT)]);
      }
    }
    __syncthreads();
    if (more) {
      *(f32x4*)&sg[t << 2] = u0;
      *(f32x4*)&sg[4096 + (t << 2)] = u1;
    }
    __syncthreads();
    u0 = v0; u1 = v1;
    c0 = c4; c1 = d1; c2 = d2; c3 = d3; c4 = d4;
    pkA = qA; pkB = qB;
  }
  int gb = k << BSHIFT;
  for (int j = t; j < 8192; j += 1024) atomicAdd(&G0[gb + j], a[j]);
}

// --- epilogues: norm/GEMV/ReLU on planes; re-zero G for the next layer ---

__global__ void k_epi1(float* __restrict__ G0, const float* __restrict__ norm,
                       const float* __restrict__ W1, const float* __restrict__ b1,
                       float* __restrict__ X0, float* __restrict__ X1, float* __restrict__ X2,
                       int N) {
  int i = blockIdx.x * 1024 + threadIdx.x;
  if (i >= N) return;
  float n = norm[i];
  float pre = G0[i] * n;
  G0[i] = 0.0f;
  X0[i] = fmaxf(0.0f, pre * W1[0] + b1[0]) * n;
  X1[i] = fmaxf(0.0f, pre * W1[1] + b1[1]) * n;
  X2[i] = fmaxf(0.0f, pre * W1[2] + b1[2]) * n;
}

__global__ void k_epi3(float* __restrict__ G0, float* __restrict__ G1, float* __restrict__ G2,
                       const float* __restrict__ norm, const float* __restrict__ W,
                       const float* __restrict__ bias,
                       float* __restrict__ X0, float* __restrict__ X1, float* __restrict__ X2,
                       int N) {
  int i = blockIdx.x * 1024 + threadIdx.x;
  if (i >= N) return;
  float n = norm[i];
  float x0 = G0[i] * n, x1 = G1[i] * n, x2 = G2[i] * n;
  G0[i] = 0.0f; G1[i] = 0.0f; G2[i] = 0.0f;
  float h0 = fmaxf(0.0f, x0 * W[0] + x1 * W[3] + x2 * W[6] + bias[0]);
  float h1 = fmaxf(0.0f, x0 * W[1] + x1 * W[4] + x2 * W[7] + bias[1]);
  float h2 = fmaxf(0.0f, x0 * W[2] + x1 * W[5] + x2 * W[8] + bias[2]);
  X0[i] = h0 * n; X1[i] = h1 * n; X2[i] = h2 * n;
}

__global__ void k_epi5(float* __restrict__ G0, float* __restrict__ G1, float* __restrict__ G2,
                       const float* __restrict__ norm, const float* __restrict__ W5,
                       const float* __restrict__ b5, const float* __restrict__ W6,
                       float* __restrict__ sB, int N) {
  int i = blockIdx.x * 1024 + threadIdx.x;
  if (i >= N) return;
  float n = norm[i];
  float x0 = G0[i] * n, x1 = G1[i] * n, x2 = G2[i] * n;
  G0[i] = 0.0f; G1[i] = 0.0f; G2[i] = 0.0f;
  float h0 = fmaxf(0.0f, x0 * W5[0] + x1 * W5[3] + x2 * W5[6] + b5[0]);
  float h1 = fmaxf(0.0f, x0 * W5[1] + x1 * W5[4] + x2 * W5[7] + b5[1]);
  float h2 = fmaxf(0.0f, x0 * W5[2] + x1 * W5[5] + x2 * W5[8] + b5[2]);
  sB[i] = (h0 * W6[0] + h1 * W6[1] + h2 * W6[2]) * n;
}

__global__ void k_epi6(const float* __restrict__ G0, const float* __restrict__ norm,
                       const float* __restrict__ b6, float* __restrict__ out, int N) {
  int i = blockIdx.x * 1024 + threadIdx.x;
  if (i >= N) return;
  out[i] = fmaxf(0.0f, G0[i] * norm[i] + b6[0]);
}

extern "C" void kernel_launch(void* const* d_in, const int* in_sizes, int n_in,
                              void* d_out, int out_size, void* d_ws, size_t ws_size,
                              hipStream_t stream) {
  const float* feat = (const float*)d_in[0];
  const float* norm = (const float*)d_in[1];
  const int* src = (const int*)d_in[2];
  const int* dst = (const int*)d_in[3];
  const float* W1 = (const float*)d_in[4];
  const float* b1 = (const float*)d_in[5];
  const float* W2 = (const float*)d_in[6];
  const float* b2 = (const float*)d_in[7];
  const float* W3 = (const float*)d_in[8];
  const float* b3 = (const float*)d_in[9];
  const float* W4 = (const float*)d_in[10];
  const float* b4 = (const float*)d_in[11];
  const float* W5 = (const float*)d_in[12];
  const float* b5 = (const float*)d_in[13];
  const float* W6 = (const float*)d_in[14];
  const float* b6 = (const float*)d_in[15];
  float* out = (float*)d_out;

  const int N = in_sizes[0];
  const int E = in_sizes[2];
  const int chunk = (((E + NBLK - 1) / NBLK) + 3) & ~3;  // 16B-aligned
  const int nbE = (N + 1023) / 1024;

  // Workspace (~92.4 MB):
  //   packed2[E] (64MB) | binStart2[65536] | s0[N] | X0[N] X1[N] X2[N] | G[3*GP]
  // Build aliases (over s0..G, dead until build done):
  //   histB[MA] | histT[MA] | scanT[MA] | partial[1024] | packed1C[<=6M]
  unsigned int* packed2 = (unsigned int*)d_ws;
  int* binStart2 = (int*)(packed2 + (size_t)E);
  float* s0 = (float*)(binStart2 + 65536);
  float* X0 = s0 + (size_t)N;
  float* X1 = X0 + (size_t)N;
  float* X2 = X1 + (size_t)N;
  float* G = X2 + (size_t)N;
  float* G0 = G, *G1 = G + GP, *G2 = G + 2 * (size_t)GP;
  int* histB = (int*)s0;  // build-phase only
  int* histT = histB + MA;
  int* scanT = histT + MA;
  int* partial = scanT + MA;
  unsigned int* packed1C = (unsigned int*)(partial + 1024);

  // --- Build phase A: hist + scan + ONE full scatter into packed2 buffer ---
  k_zeroi<<<512, 1024, 0, stream>>>(histB, MA);
  k_phist<<<NBLK, BT, 0, stream>>>(src, dst, histB, E, chunk);
  {
    dim3 g1(NBINS_A / 64, NBLK / 64);
    k_transp<<<g1, BT, 0, stream>>>(histB, histT, NBLK, NBINS_A);
  }
  k_blockSum<<<MA / BT, BT, 0, stream>>>(histT, partial, MA);
  k_scanPartials<<<1, BT, 0, stream>>>(partial, MA / BT);
  k_scanFinal<<<MA / BT, BT, 0, stream>>>(histT, partial, MA);
  {
    dim3 g2(NBLK / 64, NBINS_A / 64);  // -> scanT[256][1024]; row 0 = bin starts
    k_transp<<<g2, BT, 0, stream>>>(histT, scanT, NBINS_A, NBLK);
  }
  k_pscatterA<<<NBLK, BT, 0, stream>>>(src, dst, scanT, packed2, E, chunk);
  // --- Phase B: per-chunk span-copy + in-place refine ---
  {
    const int kLos[4] = {0, 41, 82, 123};
    for (int c = 0; c < 3; ++c) {
      int kLo = kLos[c], kHi = kLos[c + 1];
      k_copy<<<2048, 1024, 0, stream>>>(scanT, packed2, packed1C, kLo, kHi);
      k_refine<<<kHi - kLo, 1024, 0, stream>>>(scanT, packed1C, packed2, binStart2, kLo, E);
    }
  }
  // --- Zero G planes, compute s0 (after aliases are dead) ---
  k_zeroi<<<1024, 1024, 0, stream>>>((int*)G, 3 * GP);
  k_init<<<(N + BT - 1) / BT, BT, 0, stream>>>(feat, norm, s0, N);

  const int gPass = NBKT * 2;  // 246

  // --- Layer 1 (1ch in) ---
  k_pass1<<<gPass, 1024, 0, stream>>>(binStart2, packed2, s0, G0, N, E);
  k_epi1<<<nbE, 1024, 0, stream>>>(G0, norm, W1, b1, X0, X1, X2, N);
  // --- Layers 2-4 (3ch) ---
  k_pass3<<<gPass, 1024, 0, stream>>>(binStart2, packed2, X0, X1, X2, G0, G1, G2, N, E);
  k_epi3<<<nbE, 1024, 0, stream>>>(G0, G1, G2, norm, W2, b2, X0, X1, X2, N);
  k_pass3<<<gPass, 1024, 0, stream>>>(binStart2, packed2, X0, X1, X2, G0, G1, G2, N, E);
  k_epi3<<<nbE, 1024, 0, stream>>>(G0, G1, G2, norm, W3, b3, X0, X1, X2, N);
  k_pass3<<<gPass, 1024, 0, stream>>>(binStart2, packed2, X0, X1, X2, G0, G1, G2, N, E);
  k_epi3<<<nbE, 1024, 0, stream>>>(G0, G1, G2, norm, W4, b4, X0, X1, X2, N);
  // --- Layer 5 (3ch, W6 folded) -> sB in s0 buffer ---
  k_pass3<<<gPass, 1024, 0, stream>>>(binStart2, packed2, X0, X1, X2, G0, G1, G2, N, E);
  k_epi5<<<nbE, 1024, 0, stream>>>(G0, G1, G2, norm, W5, b5, W6, s0, N);
  // --- Layer 6 (1ch) ---
  k_pass1<<<gPass, 1024, 0, stream>>>(binStart2, packed2, s0, G0, N, E);
  k_epi6<<<nbE, 1024, 0, stream>>>(G0, norm, b6, out, N);
}